// Round 1
// baseline (345.853 us; speedup 1.0000x reference)
//
#include <hip/hip_runtime.h>
#include <hip/hip_bf16.h>
#include <stdint.h>

typedef float f32x4 __attribute__((ext_vector_type(4)));
typedef short s16x8 __attribute__((ext_vector_type(8)));

#define LN2F 0.6931471805599453f

static __device__ __forceinline__ f32x4 mfma16(s16x8 a, s16x8 b, f32x4 c) {
    return __builtin_amdgcn_mfma_f32_16x16x32_bf16(a, b, c, 0, 0, 0);
}

// ---------------- cos/sin table: [4096][32] ----------------
__global__ __launch_bounds__(256) void k_costab(float* __restrict__ ct, float* __restrict__ st) {
    int i = blockIdx.x * 256 + threadIdx.x;   // 131072 total
    int t = i >> 5, f = i & 31;
    float inv = powf(10000.0f, -(float)f / 32.0f);
    float a = (float)t * inv;
    ct[i] = cosf(a);
    st[i] = sinf(a);
}

// ---------------- fp32 -> bf16 convert + weight concat ----------------
// virtual concat: x[0,4194304) wq[..5242880) wk[..5505024) wv[..5767168) wo[..6815744)
__global__ __launch_bounds__(256) void k_convert(
        const float* __restrict__ x, const float* __restrict__ wq,
        const float* __restrict__ wk, const float* __restrict__ wv,
        const float* __restrict__ wo,
        __hip_bfloat16* __restrict__ xb, __hip_bfloat16* __restrict__ wb,
        __hip_bfloat16* __restrict__ wob) {
    size_t c = (size_t)blockIdx.x * 256 + threadIdx.x;
    if (c >= 1703936) return;
    size_t e = c * 4;
    const float* src;
    __hip_bfloat16* dst;
    if (e < 4194304) { src = x + e; dst = xb + e; }
    else if (e < 5242880) { src = wq + (e - 4194304); dst = wb + (e - 4194304); }
    else if (e < 5505024) { src = wk + (e - 5242880); dst = wb + (e - 4194304); }
    else if (e < 5767168) { src = wv + (e - 5505024); dst = wb + (e - 4194304); }
    else { src = wo + (e - 5767168); dst = wob + (e - 5767168); }
    float4 v = *(const float4*)src;
    ushort4 u;
    u.x = __bfloat16_as_ushort(__float2bfloat16(v.x));
    u.y = __bfloat16_as_ushort(__float2bfloat16(v.y));
    u.z = __bfloat16_as_ushort(__float2bfloat16(v.z));
    u.w = __bfloat16_as_ushort(__float2bfloat16(v.w));
    *(ushort4*)(void*)dst = u;
}

// ---------------- NT GEMM: C[M][N] = sum_k A[m][k]*B[n][k], bf16 in fp32 out ----------------
__global__ __launch_bounds__(256) void k_gemm_bt(
        const __hip_bfloat16* __restrict__ A, const __hip_bfloat16* __restrict__ B,
        float* __restrict__ C, int M, int N, int K) {
    __shared__ __hip_bfloat16 As[128][32];
    __shared__ __hip_bfloat16 Bs[128][32];
    int tid = threadIdx.x;
    int wave = tid >> 6, lane = tid & 63;
    int l15 = lane & 15, l4 = lane >> 4;
    int wr = (wave >> 1) * 64, wc = (wave & 1) * 64;
    int row0 = blockIdx.y * 128, col0 = blockIdx.x * 128;
    f32x4 acc[4][4] = {};
    int c0 = tid, c1 = tid + 256;
    int r0 = c0 >> 2, k0o = (c0 & 3) << 3;
    int r1 = c1 >> 2, k1o = (c1 & 3) << 3;
    for (int kb = 0; kb < K; kb += 32) {
        __syncthreads();
        *(s16x8*)(void*)&As[r0][k0o] = *(const s16x8*)(const void*)&A[(size_t)(row0 + r0) * K + kb + k0o];
        *(s16x8*)(void*)&As[r1][k1o] = *(const s16x8*)(const void*)&A[(size_t)(row0 + r1) * K + kb + k1o];
        *(s16x8*)(void*)&Bs[r0][k0o] = *(const s16x8*)(const void*)&B[(size_t)(col0 + r0) * K + kb + k0o];
        *(s16x8*)(void*)&Bs[r1][k1o] = *(const s16x8*)(const void*)&B[(size_t)(col0 + r1) * K + kb + k1o];
        __syncthreads();
        s16x8 af[4], bf[4];
#pragma unroll
        for (int m = 0; m < 4; m++) af[m] = *(const s16x8*)(const void*)&As[wr + m * 16 + l15][l4 * 8];
#pragma unroll
        for (int n = 0; n < 4; n++) bf[n] = *(const s16x8*)(const void*)&Bs[wc + n * 16 + l15][l4 * 8];
#pragma unroll
        for (int m = 0; m < 4; m++)
#pragma unroll
            for (int n = 0; n < 4; n++)
                acc[m][n] = mfma16(af[m], bf[n], acc[m][n]);
    }
#pragma unroll
    for (int m = 0; m < 4; m++)
#pragma unroll
        for (int n = 0; n < 4; n++)
#pragma unroll
            for (int r = 0; r < 4; r++)
                C[(size_t)(row0 + wr + m * 16 + l4 * 4 + r) * N + col0 + wc + n * 16 + l15] = acc[m][n][r];
}

// ---------------- RoPE + scatter: raw [4096][1536] fp32 -> qr/kr bf16, K/V fp32 outputs ----------------
__global__ __launch_bounds__(256) void k_rope(
        const float* __restrict__ raw, const float* __restrict__ ct, const float* __restrict__ st,
        __hip_bfloat16* __restrict__ qr, __hip_bfloat16* __restrict__ kr,
        float* __restrict__ outK, float* __restrict__ outV) {
    int t = blockIdx.x;
    int tid = threadIdx.x;
    const float* r = raw + (size_t)t * 1536;
    // Q: 16 heads x 32 pairs = 512 pairs
    for (int p = tid; p < 512; p += 256) {
        int head = p >> 5, f = p & 31;
        float a = r[head * 64 + f], b = r[head * 64 + f + 32];
        float c = ct[t * 32 + f], s = st[t * 32 + f];
        qr[(size_t)t * 1024 + head * 64 + f]      = __float2bfloat16(a * c - b * s);
        qr[(size_t)t * 1024 + head * 64 + f + 32] = __float2bfloat16(b * c + a * s);
    }
    // K: 4 kv heads x 32 pairs = 128 pairs (+ fp32 repeated output)
    if (tid < 128) {
        int kvh = tid >> 5, f = tid & 31;
        float a = r[1024 + kvh * 64 + f], b = r[1024 + kvh * 64 + f + 32];
        float c = ct[t * 32 + f], s = st[t * 32 + f];
        float ra = a * c - b * s, rb = b * c + a * s;
        kr[((size_t)kvh * 4096 + t) * 64 + f]      = __float2bfloat16(ra);
        kr[((size_t)kvh * 4096 + t) * 64 + f + 32] = __float2bfloat16(rb);
#pragma unroll
        for (int rep = 0; rep < 4; rep++) {
            outK[((size_t)(kvh * 4 + rep) * 4096 + t) * 64 + f]      = ra;
            outK[((size_t)(kvh * 4 + rep) * 4096 + t) * 64 + f + 32] = rb;
        }
    }
    // V fp32 repeated output (256 values per row)
    {
        int kvh = tid >> 6, d = tid & 63;
        float v = r[1280 + tid];
#pragma unroll
        for (int rep = 0; rep < 4; rep++)
            outV[((size_t)(kvh * 4 + rep) * 4096 + t) * 64 + d] = v;
    }
}

// ---------------- V transpose: raw V cols -> vt[4][64][4096] bf16 ----------------
__global__ __launch_bounds__(256) void k_vtrans(const float* __restrict__ raw,
                                                __hip_bfloat16* __restrict__ vt) {
    int tt = blockIdx.x, kvh = blockIdx.y;
    int tid = threadIdx.x;
    for (int w = tid; w < 512; w += 256) {
        int d = w >> 3, t8 = (w & 7) << 3;
        s16x8 p;
#pragma unroll
        for (int j = 0; j < 8; j++)
            p[j] = __bfloat16_as_short(
                __float2bfloat16(raw[(size_t)(tt * 64 + t8 + j) * 1536 + 1280 + kvh * 64 + d]));
        *(s16x8*)(void*)&vt[((size_t)kvh * 64 + d) * 4096 + tt * 64 + t8] = p;
    }
}

// ---------------- ring attention ----------------
// grid (qt=8, ib=4, h=16), 256 thr; wave w owns 32 q-rows; kv tiles of 64 keys
__global__ __launch_bounds__(256) void k_attn(
        const __hip_bfloat16* __restrict__ qr, const __hip_bfloat16* __restrict__ kr,
        const __hip_bfloat16* __restrict__ vt, __hip_bfloat16* __restrict__ ao) {
    int qt = blockIdx.x, ib = blockIdx.y, h = blockIdx.z;
    int kvh = h >> 2;
    int tid = threadIdx.x, wave = tid >> 6, lane = tid & 63;
    int l15 = lane & 15, l4 = lane >> 4;
    int qbase = ib * 1024 + qt * 128 + wave * 32;
    __shared__ __hip_bfloat16 Pl[4][32][72];  // per-wave P, pad->row stride 144B
    s16x8 qf[2][2];
#pragma unroll
    for (int m = 0; m < 2; m++)
#pragma unroll
        for (int kk = 0; kk < 2; kk++)
            qf[m][kk] = *(const s16x8*)(const void*)
                &qr[(size_t)(qbase + m * 16 + l15) * 1024 + h * 64 + kk * 32 + l4 * 8];
    f32x4 oacc[2][4] = {};
    float mrow[2][4], lrow[2][4];
#pragma unroll
    for (int m = 0; m < 2; m++)
#pragma unroll
        for (int r = 0; r < 4; r++) { mrow[m][r] = -1e30f; lrow[m][r] = 0.0f; }
    int kstart = (ib == 0) ? 0 : (ib - 1) * 1024;
    int ntiles = (ib == 0) ? 16 : 32;
    int nbias  = (ib == 0) ? 0 : 16;   // duplicated block => +ln2 logit bias
    const __hip_bfloat16* Kh = kr + (size_t)kvh * 4096 * 64;
    const __hip_bfloat16* Vh = vt + (size_t)kvh * 64 * 4096;
    for (int t = 0; t < ntiles; t++) {
        int k0 = kstart + t * 64;
        f32x4 s[2][4] = {};
#pragma unroll
        for (int kk = 0; kk < 2; kk++) {
            s16x8 kf[4];
#pragma unroll
            for (int n = 0; n < 4; n++)
                kf[n] = *(const s16x8*)(const void*)
                    &Kh[(size_t)(k0 + n * 16 + l15) * 64 + kk * 32 + l4 * 8];
#pragma unroll
            for (int m = 0; m < 2; m++)
#pragma unroll
                for (int n = 0; n < 4; n++)
                    s[m][n] = mfma16(qf[m][kk], kf[n], s[m][n]);
        }
        float bias = (t < nbias) ? LN2F : 0.0f;
        float alpha[2][4], rsum[2][4];
#pragma unroll
        for (int m = 0; m < 2; m++)
#pragma unroll
            for (int r = 0; r < 4; r++) {
                float mx = -1e30f;
#pragma unroll
                for (int n = 0; n < 4; n++) {
                    float v = s[m][n][r] * 0.125f + bias;
                    s[m][n][r] = v;
                    mx = fmaxf(mx, v);
                }
#pragma unroll
                for (int d = 1; d < 16; d <<= 1) mx = fmaxf(mx, __shfl_xor(mx, d));
                float mn = fmaxf(mrow[m][r], mx);
                alpha[m][r] = __expf(mrow[m][r] - mn);
                float sum = 0.0f;
#pragma unroll
                for (int n = 0; n < 4; n++) {
                    float p = __expf(s[m][n][r] - mn);
                    s[m][n][r] = p;
                    sum += p;
                }
#pragma unroll
                for (int d = 1; d < 16; d <<= 1) sum += __shfl_xor(sum, d);
                rsum[m][r] = sum;
                mrow[m][r] = mn;
            }
#pragma unroll
        for (int m = 0; m < 2; m++)
#pragma unroll
            for (int r = 0; r < 4; r++)
                lrow[m][r] = lrow[m][r] * alpha[m][r] + rsum[m][r];
#pragma unroll
        for (int m = 0; m < 2; m++)
#pragma unroll
            for (int n = 0; n < 4; n++)
#pragma unroll
                for (int r = 0; r < 4; r++)
                    oacc[m][n][r] *= alpha[m][r];
        // P -> LDS (transpose to A-fragment layout)
#pragma unroll
        for (int m = 0; m < 2; m++)
#pragma unroll
            for (int n = 0; n < 4; n++)
#pragma unroll
                for (int r = 0; r < 4; r++)
                    Pl[wave][m * 16 + l4 * 4 + r][n * 16 + l15] = __float2bfloat16(s[m][n][r]);
        __syncthreads();
#pragma unroll
        for (int kk = 0; kk < 2; kk++) {
            s16x8 pf[2], vf[4];
#pragma unroll
            for (int m = 0; m < 2; m++)
                pf[m] = *(const s16x8*)(const void*)&Pl[wave][m * 16 + l15][kk * 32 + l4 * 8];
#pragma unroll
            for (int n = 0; n < 4; n++)
                vf[n] = *(const s16x8*)(const void*)
                    &Vh[(size_t)(n * 16 + l15) * 4096 + k0 + kk * 32 + l4 * 8];
#pragma unroll
            for (int m = 0; m < 2; m++)
#pragma unroll
                for (int n = 0; n < 4; n++)
                    oacc[m][n] = mfma16(pf[m], vf[n], oacc[m][n]);
        }
    }
#pragma unroll
    for (int m = 0; m < 2; m++)
#pragma unroll
        for (int r = 0; r < 4; r++) {
            float inv = 1.0f / lrow[m][r];
#pragma unroll
            for (int n = 0; n < 4; n++)
                ao[(size_t)(qbase + m * 16 + l4 * 4 + r) * 1024 + h * 64 + n * 16 + l15] =
                    __float2bfloat16(oacc[m][n][r] * inv);
        }
}

extern "C" void kernel_launch(void* const* d_in, const int* in_sizes, int n_in,
                              void* d_out, int out_size, void* d_ws, size_t ws_size,
                              hipStream_t stream) {
    const float* x  = (const float*)d_in[0];
    const float* wq = (const float*)d_in[1];
    const float* wk = (const float*)d_in[2];
    const float* wv = (const float*)d_in[3];
    const float* wo = (const float*)d_in[4];
    float* out0 = (float*)d_out;
    float* outK = out0 + 4194304;
    float* outV = out0 + 8388608;
    char* ws = (char*)d_ws;
    __hip_bfloat16* xb  = (__hip_bfloat16*)(ws + 0);          // 8 MB
    __hip_bfloat16* wb  = (__hip_bfloat16*)(ws + 8388608);    // 3 MB  (wq|wk|wv rows)
    __hip_bfloat16* wob = (__hip_bfloat16*)(ws + 11534336);   // 2 MB
    float* ct           = (float*)(ws + 13631488);            // 512 KB
    float* st           = (float*)(ws + 14155776);            // 512 KB
    float* raw          = (float*)(ws + 14680064);            // 25.2 MB [4096][1536] fp32
    __hip_bfloat16* qr  = (__hip_bfloat16*)(ws + 39845888);   // 8 MB
    __hip_bfloat16* kr  = (__hip_bfloat16*)(ws + 48234496);   // 2 MB [4][4096][64]
    __hip_bfloat16* vt  = (__hip_bfloat16*)(ws + 50331648);   // 2 MB [4][64][4096]
    __hip_bfloat16* ao  = (__hip_bfloat16*)(ws + 52428800);   // 8 MB

    hipLaunchKernelGGL(k_costab, dim3(512), dim3(256), 0, stream, ct, st);
    hipLaunchKernelGGL(k_convert, dim3(6656), dim3(256), 0, stream, x, wq, wk, wv, wo, xb, wb, wob);
    hipLaunchKernelGGL(k_gemm_bt, dim3(12, 32), dim3(256), 0, stream, xb, wb, raw, 4096, 1536, 1024);
    hipLaunchKernelGGL(k_rope, dim3(4096), dim3(256), 0, stream, raw, ct, st, qr, kr, outK, outV);
    hipLaunchKernelGGL(k_vtrans, dim3(64, 4), dim3(256), 0, stream, raw, vt);
    hipLaunchKernelGGL(k_attn, dim3(8, 4, 16), dim3(256), 0, stream, qr, kr, vt, ao);
    hipLaunchKernelGGL(k_gemm_bt, dim3(8, 32), dim3(256), 0, stream, ao, wob, out0, 4096, 1024, 1024);
}